// Round 2
// baseline (317.884 us; speedup 1.0000x reference)
//
#include <hip/hip_runtime.h>
#include <cstdint>
#include <cstddef>

// ---------------------------------------------------------------------------
// ReLA block: y = LN2( (causal_relu( (LN1(x)Wq*s) (LN1(x)Wk)^T ) (LN1(x)Wv)) Wout )
// x: [2,2048,1024] fp32. HEADS=16, DIM_HEAD=64, DIM=1024. Output fp32.
// Strategy: bf16 MFMA (16x16x32) for all matmuls, fp32 accumulate.
// R1: attention rewritten barrier-free — K/V fragments direct from global
//     (registers), Ss round-trip wave-private, pair-balanced (p, 31-p).
// ---------------------------------------------------------------------------

typedef __bf16 bf16_t;
typedef __bf16 bf16x8 __attribute__((ext_vector_type(8)));
typedef __bf16 bf16x4 __attribute__((ext_vector_type(4)));
typedef float  f32x4  __attribute__((ext_vector_type(4)));

#define DEV_INLINE __device__ __forceinline__

// async global->LDS, 16B per lane. LDS dest is wave-uniform base + lane*16.
DEV_INLINE void async_copy16(void* lds, const void* g) {
  __builtin_amdgcn_global_load_lds(
      (__attribute__((address_space(1))) void*)(g),
      (__attribute__((address_space(3))) void*)(lds), 16, 0, 0);
}

// ---------------------------------------------------------------------------
// LN1: x fp32 [4096,1024] -> xn bf16 [4096,1024]
// ---------------------------------------------------------------------------
__global__ __launch_bounds__(256) void ln1_kernel(
    const float* __restrict__ x, const float* __restrict__ g,
    const float* __restrict__ bta, bf16_t* __restrict__ xn) {
  const int row = blockIdx.x;
  const int t = threadIdx.x, w = t >> 6, l = t & 63;
  const float* xr = x + (size_t)row * 1024;
  float4 v = *(const float4*)(xr + t * 4);
  float s  = v.x + v.y + v.z + v.w;
  float s2 = v.x * v.x + v.y * v.y + v.z * v.z + v.w * v.w;
  #pragma unroll
  for (int off = 32; off >= 1; off >>= 1) {
    s  += __shfl_down(s, off);
    s2 += __shfl_down(s2, off);
  }
  __shared__ float red[8];
  if (l == 0) { red[w] = s; red[4 + w] = s2; }
  __syncthreads();
  s  = red[0] + red[1] + red[2] + red[3];
  s2 = red[4] + red[5] + red[6] + red[7];
  float mu  = s * (1.0f / 1024.0f);
  float var = s2 * (1.0f / 1024.0f) - mu * mu;
  float rs  = rsqrtf(var + 1e-5f);
  float4 gv = *(const float4*)(g + t * 4);
  float4 bv = *(const float4*)(bta + t * 4);
  bf16x4 o;
  o[0] = (bf16_t)((v.x - mu) * rs * gv.x + bv.x);
  o[1] = (bf16_t)((v.y - mu) * rs * gv.y + bv.y);
  o[2] = (bf16_t)((v.z - mu) * rs * gv.z + bv.z);
  o[3] = (bf16_t)((v.w - mu) * rs * gv.w + bv.w);
  *(bf16x4*)(xn + (size_t)row * 1024 + t * 4) = o;
}

// ---------------------------------------------------------------------------
// LN2: z fp32 [4096,1024] -> out fp32 [4096,1024]
// ---------------------------------------------------------------------------
__global__ __launch_bounds__(256) void ln2_kernel(
    const float* __restrict__ z, const float* __restrict__ g,
    const float* __restrict__ bta, float* __restrict__ out) {
  const int row = blockIdx.x;
  const int t = threadIdx.x, w = t >> 6, l = t & 63;
  const float* zr = z + (size_t)row * 1024;
  float4 v = *(const float4*)(zr + t * 4);
  float s  = v.x + v.y + v.z + v.w;
  float s2 = v.x * v.x + v.y * v.y + v.z * v.z + v.w * v.w;
  #pragma unroll
  for (int off = 32; off >= 1; off >>= 1) {
    s  += __shfl_down(s, off);
    s2 += __shfl_down(s2, off);
  }
  __shared__ float red[8];
  if (l == 0) { red[w] = s; red[4 + w] = s2; }
  __syncthreads();
  s  = red[0] + red[1] + red[2] + red[3];
  s2 = red[4] + red[5] + red[6] + red[7];
  float mu  = s * (1.0f / 1024.0f);
  float var = s2 * (1.0f / 1024.0f) - mu * mu;
  float rs  = rsqrtf(var + 1e-5f);
  float4 gv = *(const float4*)(g + t * 4);
  float4 bv = *(const float4*)(bta + t * 4);
  float4 o;
  o.x = (v.x - mu) * rs * gv.x + bv.x;
  o.y = (v.y - mu) * rs * gv.y + bv.y;
  o.z = (v.z - mu) * rs * gv.z + bv.z;
  o.w = (v.w - mu) * rs * gv.w + bv.w;
  *(float4*)(out + (size_t)row * 1024 + t * 4) = o;
}

// ---------------------------------------------------------------------------
// Weight transpose+convert: w fp32 [1024][N] -> wT bf16 [N][1024]
// ---------------------------------------------------------------------------
__global__ __launch_bounds__(256) void wtrans_kernel(
    const float* __restrict__ wsrc, bf16_t* __restrict__ wdstT, int N) {
  __shared__ __align__(16) float tl[64][68];
  const int n0 = blockIdx.x * 64, k0 = blockIdx.y * 64;
  const int t = threadIdx.x;
  #pragma unroll
  for (int c = 0; c < 4; ++c) {
    int idx = c * 256 + t;
    int r = idx >> 4, c4 = (idx & 15) * 4;
    *(float4*)&tl[r][c4] = *(const float4*)(wsrc + (size_t)(k0 + r) * N + n0 + c4);
  }
  __syncthreads();
  #pragma unroll
  for (int c = 0; c < 2; ++c) {
    int idx = c * 256 + t;
    int nl = idx >> 3, kc = (idx & 7) * 8;
    bf16x8 o;
    #pragma unroll
    for (int ii = 0; ii < 8; ++ii) o[ii] = (bf16_t)tl[kc + ii][nl];
    *(bf16x8*)(wdstT + (size_t)(n0 + nl) * 1024 + k0 + kc) = o;
  }
}

// ---------------------------------------------------------------------------
// V transpose: v bf16 [b,h,n,64] -> vT bf16 [b,h,64,n]   (n=2048)
// ---------------------------------------------------------------------------
__global__ __launch_bounds__(256) void vtrans_kernel(
    const bf16_t* __restrict__ v, bf16_t* __restrict__ vT) {
  __shared__ __align__(16) bf16_t tl[64][72];
  const int n0 = blockIdx.x * 64;
  const size_t bh = blockIdx.y;
  const int t = threadIdx.x;
  #pragma unroll
  for (int c = 0; c < 2; ++c) {
    int idx = c * 256 + t;
    int r = idx >> 3, c8 = (idx & 7) * 8;
    *(bf16x8*)&tl[r][c8] = *(const bf16x8*)(v + (bh * 2048 + n0 + r) * 64 + c8);
  }
  __syncthreads();
  #pragma unroll
  for (int c = 0; c < 2; ++c) {
    int idx = c * 256 + t;
    int d = idx >> 3, nc = (idx & 7) * 8;
    bf16x8 o;
    #pragma unroll
    for (int ii = 0; ii < 8; ++ii) o[ii] = tl[nc + ii][d];
    *(bf16x8*)(vT + (bh * 64 + d) * 2048 + n0 + nc) = o;
  }
}

// ---------------------------------------------------------------------------
// GEMM: C[M,N] = A[M,1024] @ Bt[N,1024]^T, bf16 in, fp32 acc. (m97 structure)
// ---------------------------------------------------------------------------
template <int EPI>
__global__ __launch_bounds__(256, 2) void gemm128_kernel(
    const bf16_t* __restrict__ A, const bf16_t* __restrict__ Bt,
    void* __restrict__ C0, void* __restrict__ C1, void* __restrict__ C2) {
  __shared__ __align__(16) bf16_t As[128 * 32];
  __shared__ __align__(16) bf16_t Bs[128 * 32];
  const int t = threadIdx.x;
  const int w = t >> 6, l = t & 63, l15 = l & 15, quad = l >> 4;
  const int wy = w >> 1, wx = w & 1;
  const int m0 = blockIdx.y * 128, n0 = blockIdx.x * 128;

  int arow[2], acol[2];
  #pragma unroll
  for (int c = 0; c < 2; ++c) {
    int e = (w * 2 + c) * 512 + l * 8;
    arow[c] = e >> 5;
    acol[c] = e & 31;
  }

  f32x4 acc[4][4];
  #pragma unroll
  for (int i = 0; i < 4; ++i)
    #pragma unroll
    for (int j = 0; j < 4; ++j) acc[i][j] = (f32x4)0.0f;

  for (int kt = 0; kt < 32; ++kt) {
    __syncthreads();
    #pragma unroll
    for (int c = 0; c < 2; ++c) {
      async_copy16(&As[(w * 2 + c) * 512],
                   A + (size_t)(m0 + arow[c]) * 1024 + kt * 32 + acol[c]);
      async_copy16(&Bs[(w * 2 + c) * 512],
                   Bt + (size_t)(n0 + arow[c]) * 1024 + kt * 32 + acol[c]);
    }
    __syncthreads();
    bf16x8 af[4], bfr[4];
    #pragma unroll
    for (int i = 0; i < 4; ++i)
      af[i] = *(const bf16x8*)&As[(wy * 64 + i * 16 + l15) * 32 + quad * 8];
    #pragma unroll
    for (int j = 0; j < 4; ++j)
      bfr[j] = *(const bf16x8*)&Bs[(wx * 64 + j * 16 + l15) * 32 + quad * 8];
    #pragma unroll
    for (int i = 0; i < 4; ++i)
      #pragma unroll
      for (int j = 0; j < 4; ++j)
        acc[i][j] = __builtin_amdgcn_mfma_f32_16x16x32_bf16(af[i], bfr[j], acc[i][j], 0, 0, 0);
  }

  if (EPI == 0) {
    float* C = (float*)C0;
    #pragma unroll
    for (int i = 0; i < 4; ++i)
      #pragma unroll
      for (int j = 0; j < 4; ++j)
        #pragma unroll
        for (int r = 0; r < 4; ++r) {
          int m = m0 + wy * 64 + i * 16 + quad * 4 + r;
          int n = n0 + wx * 64 + j * 16 + l15;
          C[(size_t)m * 1024 + n] = acc[i][j][r];
        }
  } else {
    int nb = n0 + wx * 64;
    int which = nb >> 10;
    int head = (nb & 1023) >> 6;
    bf16_t* dst = which == 0 ? (bf16_t*)C0 : which == 1 ? (bf16_t*)C1 : (bf16_t*)C2;
    float sc = which == 0 ? 0.125f : 1.0f;
    #pragma unroll
    for (int i = 0; i < 4; ++i)
      #pragma unroll
      for (int j = 0; j < 4; ++j)
        #pragma unroll
        for (int r = 0; r < 4; ++r) {
          int m = m0 + wy * 64 + i * 16 + quad * 4 + r;
          int bq = m >> 11, pos = m & 2047;
          int d = j * 16 + l15;
          dst[(((size_t)(bq * 16 + head)) * 2048 + pos) * 64 + d] =
              (bf16_t)(acc[i][j][r] * sc);
        }
  }
}

// ---------------------------------------------------------------------------
// Causal ReLU attention, R1: barrier-free.
// Block = (pair p, h, b), 256 thr / 4 waves. Handles 64-row q sub-tiles
// tA = p and tB = 31-p (uniform 33 key-tile units per block).
// Wave w owns rows [w*16, w*16+16) of each sub-tile.
// Q fragments cached in VGPRs. K/V B-fragments loaded straight from global
// (16B contiguous, identical across waves -> L1 hits). Ss (C->A layout
// round-trip) is wave-private: NO __syncthreads anywhere.
// q,k: [b,h,2048,64] bf16 (q pre-scaled by 0.125). vT: [b,h,64,2048] bf16.
// out: [b,2048,1024] bf16 (col = h*64+d).
// ---------------------------------------------------------------------------
__global__ __launch_bounds__(256) void attn_kernel(
    const bf16_t* __restrict__ q, const bf16_t* __restrict__ k,
    const bf16_t* __restrict__ vT, bf16_t* __restrict__ out) {
  __shared__ __align__(16) bf16_t Ss[64 * 72];  // 9216 B, wave-private rows

  const int p = blockIdx.x, h = blockIdx.y, b = blockIdx.z;
  const int t = threadIdx.x;
  const int w = t >> 6, l = t & 63, l15 = l & 15, quad = l >> 4;
  const size_t bh = (size_t)(b * 16 + h);
  const int tidx[2] = {p, 31 - p};                 // tile A, tile B
  const int tA = tidx[0], tB = tidx[1];

  // Q A-fragments in registers: qa[tile][kk], lane holds Q[row0+l15][kk*32+quad*8 ..+8)
  bf16x8 qa[2][2];
  #pragma unroll
  for (int tt = 0; tt < 2; ++tt) {
    int r0 = tidx[tt] * 64 + w * 16;
    #pragma unroll
    for (int kk = 0; kk < 2; ++kk)
      qa[tt][kk] = *(const bf16x8*)(q + (bh * 2048 + r0 + l15) * 64 + kk * 32 + quad * 8);
  }

  f32x4 acc[2][4];
  #pragma unroll
  for (int tt = 0; tt < 2; ++tt)
    #pragma unroll
    for (int tj = 0; tj < 4; ++tj) acc[tt][tj] = (f32x4)0.0f;

  const int nkt = tB + 1;
  for (int kt = 0; kt < nkt; ++kt) {
    // K/V B-fragments straight from global — identical across the 4 waves.
    bf16x8 bk[2][4], bv[2][4];
    #pragma unroll
    for (int kk = 0; kk < 2; ++kk)
      #pragma unroll
      for (int tj = 0; tj < 4; ++tj) {
        bk[kk][tj] = *(const bf16x8*)(k  + (bh * 2048 + kt * 64 + tj * 16 + l15) * 64
                                         + kk * 32 + quad * 8);
        bv[kk][tj] = *(const bf16x8*)(vT + (bh * 64 + tj * 16 + l15) * 2048
                                         + kt * 64 + kk * 32 + quad * 8);
      }

    const int t0 = (kt <= tA) ? 0 : 1;  // tile A participates only while kt <= tA
    for (int tt = t0; tt < 2; ++tt) {
      // S = Q . K^T  (16 rows x 64 cols per wave)
      f32x4 sacc[4];
      #pragma unroll
      for (int tj = 0; tj < 4; ++tj) sacc[tj] = (f32x4)0.0f;
      #pragma unroll
      for (int kk = 0; kk < 2; ++kk)
        #pragma unroll
        for (int tj = 0; tj < 4; ++tj)
          sacc[tj] = __builtin_amdgcn_mfma_f32_16x16x32_bf16(qa[tt][kk], bk[kk][tj], sacc[tj], 0, 0, 0);

      // relu + causal mask; C-layout -> A-layout via wave-private LDS rows
      const bool dg = (kt == tidx[tt]);  // diagonal tile
      #pragma unroll
      for (int tj = 0; tj < 4; ++tj)
        #pragma unroll
        for (int r = 0; r < 4; ++r) {
          float v = fmaxf(sacc[tj][r], 0.0f);
          if (dg && (tj * 16 + l15 > w * 16 + quad * 4 + r)) v = 0.0f;
          Ss[(w * 16 + quad * 4 + r) * 72 + tj * 16 + l15] = (bf16_t)v;
        }
      // O += S . V   (wave reads back only its own rows; lgkmcnt orders RAW)
      #pragma unroll
      for (int kk = 0; kk < 2; ++kk) {
        bf16x8 as_ = *(const bf16x8*)&Ss[(w * 16 + l15) * 72 + kk * 32 + quad * 8];
        #pragma unroll
        for (int tj = 0; tj < 4; ++tj)
          acc[tt][tj] = __builtin_amdgcn_mfma_f32_16x16x32_bf16(as_, bv[kk][tj], acc[tt][tj], 0, 0, 0);
      }
    }
  }

  // epilogue: out[b][pos][h*64+d]
  #pragma unroll
  for (int tt = 0; tt < 2; ++tt)
    #pragma unroll
    for (int tj = 0; tj < 4; ++tj)
      #pragma unroll
      for (int r = 0; r < 4; ++r) {
        int pos = tidx[tt] * 64 + w * 16 + quad * 4 + r;
        int col = h * 64 + tj * 16 + l15;
        out[((size_t)b * 2048 + pos) * 1024 + col] = (bf16_t)acc[tt][tj][r];
      }
}

// ---------------------------------------------------------------------------
// launch
// ---------------------------------------------------------------------------
extern "C" void kernel_launch(void* const* d_in, const int* in_sizes, int n_in,
                              void* d_out, int out_size, void* d_ws, size_t ws_size,
                              hipStream_t stream) {
  (void)in_sizes; (void)n_in; (void)out_size; (void)ws_size;
  const float* x     = (const float*)d_in[0];
  const float* ln1_g = (const float*)d_in[1];
  const float* ln1_b = (const float*)d_in[2];
  const float* w_qkv = (const float*)d_in[3];
  const float* w_out = (const float*)d_in[4];
  const float* ln2_g = (const float*)d_in[5];
  const float* ln2_b = (const float*)d_in[6];
  float* out = (float*)d_out;

  char* ws = (char*)d_ws;
  bf16_t* xn     = (bf16_t*)(ws + 0);          //  8,388,608  [4096,1024]
  bf16_t* wqkvT  = (bf16_t*)(ws + 8388608);    //  6,291,456  [3072,1024]
  bf16_t* woutT  = (bf16_t*)(ws + 14680064);   //  2,097,152  [1024,1024]
  bf16_t* qb     = (bf16_t*)(ws + 16777216);   //  8,388,608  [2,16,2048,64]
  bf16_t* kb     = (bf16_t*)(ws + 25165824);   //  8,388,608
  bf16_t* vb     = (bf16_t*)(ws + 33554432);   //  8,388,608
  bf16_t* vTb    = (bf16_t*)(ws + 41943040);   //  8,388,608  [2,16,64,2048]
  bf16_t* ao     = (bf16_t*)(ws + 50331648);   //  8,388,608  [4096,1024]
  float*  z      = (float*)(ws + 58720256);    // 16,777,216  [4096,1024]

  ln1_kernel<<<4096, 256, 0, stream>>>(x, ln1_g, ln1_b, xn);
  wtrans_kernel<<<dim3(48, 16), 256, 0, stream>>>(w_qkv, wqkvT, 3072);
  wtrans_kernel<<<dim3(16, 16), 256, 0, stream>>>(w_out, woutT, 1024);
  gemm128_kernel<1><<<dim3(24, 32), 256, 0, stream>>>(xn, wqkvT, qb, kb, vb);
  vtrans_kernel<<<dim3(32, 32), 256, 0, stream>>>(vb, vTb);
  attn_kernel<<<dim3(16, 16, 2), 256, 0, stream>>>(qb, kb, vTb, ao);
  gemm128_kernel<0><<<dim3(8, 32), 256, 0, stream>>>(ao, woutT, z, nullptr, nullptr);
  ln2_kernel<<<4096, 256, 0, stream>>>(z, ln2_g, ln2_b, out);
}

// Round 3
// 274.706 us; speedup vs baseline: 1.1572x; 1.1572x over previous
//
#include <hip/hip_runtime.h>
#include <cstdint>
#include <cstddef>

// ---------------------------------------------------------------------------
// ReLA block: y = LN2( (causal_relu( (LN1(x)Wq*s) (LN1(x)Wk)^T ) (LN1(x)Wv)) Wout )
// x: [2,2048,1024] fp32. HEADS=16, DIM_HEAD=64, DIM=1024. Output fp32.
// bf16 MFMA (16x16x32) everywhere, fp32 accumulate.
// R2: fix R1's catastrophic scratch spill — the tile loop had a RUNTIME lower
//     bound, making acc[tt]/qa[tt] dynamically indexed -> demoted to scratch
//     (173 MB HBM writes). Now statically unrolled with a uniform guard.
// ---------------------------------------------------------------------------

typedef __bf16 bf16_t;
typedef __bf16 bf16x8 __attribute__((ext_vector_type(8)));
typedef __bf16 bf16x4 __attribute__((ext_vector_type(4)));
typedef float  f32x4  __attribute__((ext_vector_type(4)));

#define DEV_INLINE __device__ __forceinline__

// async global->LDS, 16B per lane. LDS dest is wave-uniform base + lane*16.
DEV_INLINE void async_copy16(void* lds, const void* g) {
  __builtin_amdgcn_global_load_lds(
      (__attribute__((address_space(1))) void*)(g),
      (__attribute__((address_space(3))) void*)(lds), 16, 0, 0);
}

// ---------------------------------------------------------------------------
// LN1: x fp32 [4096,1024] -> xn bf16 [4096,1024]
// ---------------------------------------------------------------------------
__global__ __launch_bounds__(256) void ln1_kernel(
    const float* __restrict__ x, const float* __restrict__ g,
    const float* __restrict__ bta, bf16_t* __restrict__ xn) {
  const int row = blockIdx.x;
  const int t = threadIdx.x, w = t >> 6, l = t & 63;
  const float* xr = x + (size_t)row * 1024;
  float4 v = *(const float4*)(xr + t * 4);
  float s  = v.x + v.y + v.z + v.w;
  float s2 = v.x * v.x + v.y * v.y + v.z * v.z + v.w * v.w;
  #pragma unroll
  for (int off = 32; off >= 1; off >>= 1) {
    s  += __shfl_down(s, off);
    s2 += __shfl_down(s2, off);
  }
  __shared__ float red[8];
  if (l == 0) { red[w] = s; red[4 + w] = s2; }
  __syncthreads();
  s  = red[0] + red[1] + red[2] + red[3];
  s2 = red[4] + red[5] + red[6] + red[7];
  float mu  = s * (1.0f / 1024.0f);
  float var = s2 * (1.0f / 1024.0f) - mu * mu;
  float rs  = rsqrtf(var + 1e-5f);
  float4 gv = *(const float4*)(g + t * 4);
  float4 bv = *(const float4*)(bta + t * 4);
  bf16x4 o;
  o[0] = (bf16_t)((v.x - mu) * rs * gv.x + bv.x);
  o[1] = (bf16_t)((v.y - mu) * rs * gv.y + bv.y);
  o[2] = (bf16_t)((v.z - mu) * rs * gv.z + bv.z);
  o[3] = (bf16_t)((v.w - mu) * rs * gv.w + bv.w);
  *(bf16x4*)(xn + (size_t)row * 1024 + t * 4) = o;
}

// ---------------------------------------------------------------------------
// LN2: z fp32 [4096,1024] -> out fp32 [4096,1024]
// ---------------------------------------------------------------------------
__global__ __launch_bounds__(256) void ln2_kernel(
    const float* __restrict__ z, const float* __restrict__ g,
    const float* __restrict__ bta, float* __restrict__ out) {
  const int row = blockIdx.x;
  const int t = threadIdx.x, w = t >> 6, l = t & 63;
  const float* zr = z + (size_t)row * 1024;
  float4 v = *(const float4*)(zr + t * 4);
  float s  = v.x + v.y + v.z + v.w;
  float s2 = v.x * v.x + v.y * v.y + v.z * v.z + v.w * v.w;
  #pragma unroll
  for (int off = 32; off >= 1; off >>= 1) {
    s  += __shfl_down(s, off);
    s2 += __shfl_down(s2, off);
  }
  __shared__ float red[8];
  if (l == 0) { red[w] = s; red[4 + w] = s2; }
  __syncthreads();
  s  = red[0] + red[1] + red[2] + red[3];
  s2 = red[4] + red[5] + red[6] + red[7];
  float mu  = s * (1.0f / 1024.0f);
  float var = s2 * (1.0f / 1024.0f) - mu * mu;
  float rs  = rsqrtf(var + 1e-5f);
  float4 gv = *(const float4*)(g + t * 4);
  float4 bv = *(const float4*)(bta + t * 4);
  float4 o;
  o.x = (v.x - mu) * rs * gv.x + bv.x;
  o.y = (v.y - mu) * rs * gv.y + bv.y;
  o.z = (v.z - mu) * rs * gv.z + bv.z;
  o.w = (v.w - mu) * rs * gv.w + bv.w;
  *(float4*)(out + (size_t)row * 1024 + t * 4) = o;
}

// ---------------------------------------------------------------------------
// Weight transpose+convert: w fp32 [1024][N] -> wT bf16 [N][1024]
// ---------------------------------------------------------------------------
__global__ __launch_bounds__(256) void wtrans_kernel(
    const float* __restrict__ wsrc, bf16_t* __restrict__ wdstT, int N) {
  __shared__ __align__(16) float tl[64][68];
  const int n0 = blockIdx.x * 64, k0 = blockIdx.y * 64;
  const int t = threadIdx.x;
  #pragma unroll
  for (int c = 0; c < 4; ++c) {
    int idx = c * 256 + t;
    int r = idx >> 4, c4 = (idx & 15) * 4;
    *(float4*)&tl[r][c4] = *(const float4*)(wsrc + (size_t)(k0 + r) * N + n0 + c4);
  }
  __syncthreads();
  #pragma unroll
  for (int c = 0; c < 2; ++c) {
    int idx = c * 256 + t;
    int nl = idx >> 3, kc = (idx & 7) * 8;
    bf16x8 o;
    #pragma unroll
    for (int ii = 0; ii < 8; ++ii) o[ii] = (bf16_t)tl[kc + ii][nl];
    *(bf16x8*)(wdstT + (size_t)(n0 + nl) * 1024 + k0 + kc) = o;
  }
}

// ---------------------------------------------------------------------------
// V transpose: v bf16 [b,h,n,64] -> vT bf16 [b,h,64,n]   (n=2048)
// ---------------------------------------------------------------------------
__global__ __launch_bounds__(256) void vtrans_kernel(
    const bf16_t* __restrict__ v, bf16_t* __restrict__ vT) {
  __shared__ __align__(16) bf16_t tl[64][72];
  const int n0 = blockIdx.x * 64;
  const size_t bh = blockIdx.y;
  const int t = threadIdx.x;
  #pragma unroll
  for (int c = 0; c < 2; ++c) {
    int idx = c * 256 + t;
    int r = idx >> 3, c8 = (idx & 7) * 8;
    *(bf16x8*)&tl[r][c8] = *(const bf16x8*)(v + (bh * 2048 + n0 + r) * 64 + c8);
  }
  __syncthreads();
  #pragma unroll
  for (int c = 0; c < 2; ++c) {
    int idx = c * 256 + t;
    int d = idx >> 3, nc = (idx & 7) * 8;
    bf16x8 o;
    #pragma unroll
    for (int ii = 0; ii < 8; ++ii) o[ii] = tl[nc + ii][d];
    *(bf16x8*)(vT + (bh * 64 + d) * 2048 + n0 + nc) = o;
  }
}

// ---------------------------------------------------------------------------
// GEMM: C[M,N] = A[M,1024] @ Bt[N,1024]^T, bf16 in, fp32 acc. (m97 structure)
// ---------------------------------------------------------------------------
template <int EPI>
__global__ __launch_bounds__(256, 2) void gemm128_kernel(
    const bf16_t* __restrict__ A, const bf16_t* __restrict__ Bt,
    void* __restrict__ C0, void* __restrict__ C1, void* __restrict__ C2) {
  __shared__ __align__(16) bf16_t As[128 * 32];
  __shared__ __align__(16) bf16_t Bs[128 * 32];
  const int t = threadIdx.x;
  const int w = t >> 6, l = t & 63, l15 = l & 15, quad = l >> 4;
  const int wy = w >> 1, wx = w & 1;
  const int m0 = blockIdx.y * 128, n0 = blockIdx.x * 128;

  int arow[2], acol[2];
  #pragma unroll
  for (int c = 0; c < 2; ++c) {
    int e = (w * 2 + c) * 512 + l * 8;
    arow[c] = e >> 5;
    acol[c] = e & 31;
  }

  f32x4 acc[4][4];
  #pragma unroll
  for (int i = 0; i < 4; ++i)
    #pragma unroll
    for (int j = 0; j < 4; ++j) acc[i][j] = (f32x4)0.0f;

  for (int kt = 0; kt < 32; ++kt) {
    __syncthreads();
    #pragma unroll
    for (int c = 0; c < 2; ++c) {
      async_copy16(&As[(w * 2 + c) * 512],
                   A + (size_t)(m0 + arow[c]) * 1024 + kt * 32 + acol[c]);
      async_copy16(&Bs[(w * 2 + c) * 512],
                   Bt + (size_t)(n0 + arow[c]) * 1024 + kt * 32 + acol[c]);
    }
    __syncthreads();
    bf16x8 af[4], bfr[4];
    #pragma unroll
    for (int i = 0; i < 4; ++i)
      af[i] = *(const bf16x8*)&As[(wy * 64 + i * 16 + l15) * 32 + quad * 8];
    #pragma unroll
    for (int j = 0; j < 4; ++j)
      bfr[j] = *(const bf16x8*)&Bs[(wx * 64 + j * 16 + l15) * 32 + quad * 8];
    #pragma unroll
    for (int i = 0; i < 4; ++i)
      #pragma unroll
      for (int j = 0; j < 4; ++j)
        acc[i][j] = __builtin_amdgcn_mfma_f32_16x16x32_bf16(af[i], bfr[j], acc[i][j], 0, 0, 0);
  }

  if (EPI == 0) {
    float* C = (float*)C0;
    #pragma unroll
    for (int i = 0; i < 4; ++i)
      #pragma unroll
      for (int j = 0; j < 4; ++j)
        #pragma unroll
        for (int r = 0; r < 4; ++r) {
          int m = m0 + wy * 64 + i * 16 + quad * 4 + r;
          int n = n0 + wx * 64 + j * 16 + l15;
          C[(size_t)m * 1024 + n] = acc[i][j][r];
        }
  } else {
    int nb = n0 + wx * 64;
    int which = nb >> 10;
    int head = (nb & 1023) >> 6;
    bf16_t* dst = which == 0 ? (bf16_t*)C0 : which == 1 ? (bf16_t*)C1 : (bf16_t*)C2;
    float sc = which == 0 ? 0.125f : 1.0f;
    #pragma unroll
    for (int i = 0; i < 4; ++i)
      #pragma unroll
      for (int j = 0; j < 4; ++j)
        #pragma unroll
        for (int r = 0; r < 4; ++r) {
          int m = m0 + wy * 64 + i * 16 + quad * 4 + r;
          int bq = m >> 11, pos = m & 2047;
          int d = j * 16 + l15;
          dst[(((size_t)(bq * 16 + head)) * 2048 + pos) * 64 + d] =
              (bf16_t)(acc[i][j][r] * sc);
        }
  }
}

// ---------------------------------------------------------------------------
// Causal ReLU attention, R2: barrier-free + statically-indexed registers.
// Block = (pair p, h, b). Sub-tiles tA=p, tB=31-p (33 key-tile units/block).
// Wave w owns rows [w*16, w*16+16) of each sub-tile.
// Q fragments in VGPRs; K/V B-fragments straight from global (L1-served
// cross-wave duplication); Ss C->A round-trip is wave-private (no barrier).
// The tile loop is STATICALLY unrolled (tt=0,1) with a block-uniform guard —
// acc/qa stay in registers (R1's runtime-bounded loop spilled them).
// ---------------------------------------------------------------------------
__global__ __launch_bounds__(256) void attn_kernel(
    const bf16_t* __restrict__ q, const bf16_t* __restrict__ k,
    const bf16_t* __restrict__ vT, bf16_t* __restrict__ out) {
  __shared__ __align__(16) bf16_t Ss[64 * 72];  // 9216 B, wave-private rows

  const int p = blockIdx.x, h = blockIdx.y, b = blockIdx.z;
  const int t = threadIdx.x;
  const int w = t >> 6, l = t & 63, l15 = l & 15, quad = l >> 4;
  const size_t bh = (size_t)(b * 16 + h);
  const int tidx[2] = {p, 31 - p};  // compile-time-indexed only

  bf16x8 qa[2][2];
  #pragma unroll
  for (int tt = 0; tt < 2; ++tt) {
    int r0 = tidx[tt] * 64 + w * 16;
    #pragma unroll
    for (int kk = 0; kk < 2; ++kk)
      qa[tt][kk] = *(const bf16x8*)(q + (bh * 2048 + r0 + l15) * 64 + kk * 32 + quad * 8);
  }

  f32x4 acc[2][4];
  #pragma unroll
  for (int tt = 0; tt < 2; ++tt)
    #pragma unroll
    for (int tj = 0; tj < 4; ++tj) acc[tt][tj] = (f32x4)0.0f;

  const int nkt = tidx[1] + 1;
  for (int kt = 0; kt < nkt; ++kt) {
    // K/V B-fragments straight from global — identical across the 4 waves.
    bf16x8 bk[2][4], bv[2][4];
    #pragma unroll
    for (int kk = 0; kk < 2; ++kk)
      #pragma unroll
      for (int tj = 0; tj < 4; ++tj) {
        bk[kk][tj] = *(const bf16x8*)(k  + (bh * 2048 + kt * 64 + tj * 16 + l15) * 64
                                         + kk * 32 + quad * 8);
        bv[kk][tj] = *(const bf16x8*)(vT + (bh * 64 + tj * 16 + l15) * 2048
                                         + kt * 64 + kk * 32 + quad * 8);
      }

    #pragma unroll
    for (int tt = 0; tt < 2; ++tt) {
      if (kt <= tidx[tt]) {  // block-uniform; tt is compile-time
        // S = Q . K^T  (16 rows x 64 cols per wave)
        f32x4 sacc[4];
        #pragma unroll
        for (int tj = 0; tj < 4; ++tj) sacc[tj] = (f32x4)0.0f;
        #pragma unroll
        for (int kk = 0; kk < 2; ++kk)
          #pragma unroll
          for (int tj = 0; tj < 4; ++tj)
            sacc[tj] = __builtin_amdgcn_mfma_f32_16x16x32_bf16(qa[tt][kk], bk[kk][tj], sacc[tj], 0, 0, 0);

        // relu + causal mask; C-layout -> A-layout via wave-private LDS rows
        const bool dg = (kt == tidx[tt]);
        #pragma unroll
        for (int tj = 0; tj < 4; ++tj)
          #pragma unroll
          for (int r = 0; r < 4; ++r) {
            float v = fmaxf(sacc[tj][r], 0.0f);
            if (dg && (tj * 16 + l15 > w * 16 + quad * 4 + r)) v = 0.0f;
            Ss[(w * 16 + quad * 4 + r) * 72 + tj * 16 + l15] = (bf16_t)v;
          }
        // O += S . V   (wave reads only its own rows; lgkmcnt orders RAW)
        #pragma unroll
        for (int kk = 0; kk < 2; ++kk) {
          bf16x8 as_ = *(const bf16x8*)&Ss[(w * 16 + l15) * 72 + kk * 32 + quad * 8];
          #pragma unroll
          for (int tj = 0; tj < 4; ++tj)
            acc[tt][tj] = __builtin_amdgcn_mfma_f32_16x16x32_bf16(as_, bv[kk][tj], acc[tt][tj], 0, 0, 0);
        }
      }
    }
  }

  // epilogue: out[b][pos][h*64+d]
  #pragma unroll
  for (int tt = 0; tt < 2; ++tt)
    #pragma unroll
    for (int tj = 0; tj < 4; ++tj)
      #pragma unroll
      for (int r = 0; r < 4; ++r) {
        int pos = tidx[tt] * 64 + w * 16 + quad * 4 + r;
        int col = h * 64 + tj * 16 + l15;
        out[((size_t)b * 2048 + pos) * 1024 + col] = (bf16_t)acc[tt][tj][r];
      }
}

// ---------------------------------------------------------------------------
// launch
// ---------------------------------------------------------------------------
extern "C" void kernel_launch(void* const* d_in, const int* in_sizes, int n_in,
                              void* d_out, int out_size, void* d_ws, size_t ws_size,
                              hipStream_t stream) {
  (void)in_sizes; (void)n_in; (void)out_size; (void)ws_size;
  const float* x     = (const float*)d_in[0];
  const float* ln1_g = (const float*)d_in[1];
  const float* ln1_b = (const float*)d_in[2];
  const float* w_qkv = (const float*)d_in[3];
  const float* w_out = (const float*)d_in[4];
  const float* ln2_g = (const float*)d_in[5];
  const float* ln2_b = (const float*)d_in[6];
  float* out = (float*)d_out;

  char* ws = (char*)d_ws;
  bf16_t* xn     = (bf16_t*)(ws + 0);          //  8,388,608  [4096,1024]
  bf16_t* wqkvT  = (bf16_t*)(ws + 8388608);    //  6,291,456  [3072,1024]
  bf16_t* woutT  = (bf16_t*)(ws + 14680064);   //  2,097,152  [1024,1024]
  bf16_t* qb     = (bf16_t*)(ws + 16777216);   //  8,388,608  [2,16,2048,64]
  bf16_t* kb     = (bf16_t*)(ws + 25165824);   //  8,388,608
  bf16_t* vb     = (bf16_t*)(ws + 33554432);   //  8,388,608
  bf16_t* vTb    = (bf16_t*)(ws + 41943040);   //  8,388,608  [2,16,64,2048]
  bf16_t* ao     = (bf16_t*)(ws + 50331648);   //  8,388,608  [4096,1024]
  float*  z      = (float*)(ws + 58720256);    // 16,777,216  [4096,1024]

  ln1_kernel<<<4096, 256, 0, stream>>>(x, ln1_g, ln1_b, xn);
  wtrans_kernel<<<dim3(48, 16), 256, 0, stream>>>(w_qkv, wqkvT, 3072);
  wtrans_kernel<<<dim3(16, 16), 256, 0, stream>>>(w_out, woutT, 1024);
  gemm128_kernel<1><<<dim3(24, 32), 256, 0, stream>>>(xn, wqkvT, qb, kb, vb);
  vtrans_kernel<<<dim3(32, 32), 256, 0, stream>>>(vb, vTb);
  attn_kernel<<<dim3(16, 16, 2), 256, 0, stream>>>(qb, kb, vTb, ao);
  gemm128_kernel<0><<<dim3(8, 32), 256, 0, stream>>>(ao, woutT, z, nullptr, nullptr);
  ln2_kernel<<<4096, 256, 0, stream>>>(z, ln2_g, ln2_b, out);
}

// Round 4
// 198.565 us; speedup vs baseline: 1.6009x; 1.3835x over previous
//
#include <hip/hip_runtime.h>
#include <cstdint>
#include <cstddef>

// ---------------------------------------------------------------------------
// ReLA block: y = LN2( (causal_relu( (LN1(x)Wq*s) (LN1(x)Wk)^T ) (LN1(x)Wv)) Wout )
// x: [2,2048,1024] fp32. HEADS=16, DIM_HEAD=64, DIM=1024. Output fp32.
// bf16 MFMA (16x16x32) everywhere, fp32 accumulate.
// R3 attention: pair-balanced blocks + double-buffered global_load_lds K/V
//   staging (one barrier/tile, zero VGPR cost) + XOR-swizzled LDS layout
//   (2-way conflict-free b128 reads) + wave-private Ss round-trip.
//   R2's register-resident K/V was VGPR-starved -> serialized vmcnt waits.
// ---------------------------------------------------------------------------

typedef __bf16 bf16_t;
typedef __bf16 bf16x8 __attribute__((ext_vector_type(8)));
typedef __bf16 bf16x4 __attribute__((ext_vector_type(4)));
typedef float  f32x4  __attribute__((ext_vector_type(4)));

#define DEV_INLINE __device__ __forceinline__

// async global->LDS, 16B per lane. LDS dest is wave-uniform base + lane*16.
DEV_INLINE void async_copy16(void* lds, const void* g) {
  __builtin_amdgcn_global_load_lds(
      (__attribute__((address_space(1))) void*)(g),
      (__attribute__((address_space(3))) void*)(lds), 16, 0, 0);
}

// ---------------------------------------------------------------------------
// LN1: x fp32 [4096,1024] -> xn bf16 [4096,1024]
// ---------------------------------------------------------------------------
__global__ __launch_bounds__(256) void ln1_kernel(
    const float* __restrict__ x, const float* __restrict__ g,
    const float* __restrict__ bta, bf16_t* __restrict__ xn) {
  const int row = blockIdx.x;
  const int t = threadIdx.x, w = t >> 6, l = t & 63;
  const float* xr = x + (size_t)row * 1024;
  float4 v = *(const float4*)(xr + t * 4);
  float s  = v.x + v.y + v.z + v.w;
  float s2 = v.x * v.x + v.y * v.y + v.z * v.z + v.w * v.w;
  #pragma unroll
  for (int off = 32; off >= 1; off >>= 1) {
    s  += __shfl_down(s, off);
    s2 += __shfl_down(s2, off);
  }
  __shared__ float red[8];
  if (l == 0) { red[w] = s; red[4 + w] = s2; }
  __syncthreads();
  s  = red[0] + red[1] + red[2] + red[3];
  s2 = red[4] + red[5] + red[6] + red[7];
  float mu  = s * (1.0f / 1024.0f);
  float var = s2 * (1.0f / 1024.0f) - mu * mu;
  float rs  = rsqrtf(var + 1e-5f);
  float4 gv = *(const float4*)(g + t * 4);
  float4 bv = *(const float4*)(bta + t * 4);
  bf16x4 o;
  o[0] = (bf16_t)((v.x - mu) * rs * gv.x + bv.x);
  o[1] = (bf16_t)((v.y - mu) * rs * gv.y + bv.y);
  o[2] = (bf16_t)((v.z - mu) * rs * gv.z + bv.z);
  o[3] = (bf16_t)((v.w - mu) * rs * gv.w + bv.w);
  *(bf16x4*)(xn + (size_t)row * 1024 + t * 4) = o;
}

// ---------------------------------------------------------------------------
// LN2: z fp32 [4096,1024] -> out fp32 [4096,1024]
// ---------------------------------------------------------------------------
__global__ __launch_bounds__(256) void ln2_kernel(
    const float* __restrict__ z, const float* __restrict__ g,
    const float* __restrict__ bta, float* __restrict__ out) {
  const int row = blockIdx.x;
  const int t = threadIdx.x, w = t >> 6, l = t & 63;
  const float* zr = z + (size_t)row * 1024;
  float4 v = *(const float4*)(zr + t * 4);
  float s  = v.x + v.y + v.z + v.w;
  float s2 = v.x * v.x + v.y * v.y + v.z * v.z + v.w * v.w;
  #pragma unroll
  for (int off = 32; off >= 1; off >>= 1) {
    s  += __shfl_down(s, off);
    s2 += __shfl_down(s2, off);
  }
  __shared__ float red[8];
  if (l == 0) { red[w] = s; red[4 + w] = s2; }
  __syncthreads();
  s  = red[0] + red[1] + red[2] + red[3];
  s2 = red[4] + red[5] + red[6] + red[7];
  float mu  = s * (1.0f / 1024.0f);
  float var = s2 * (1.0f / 1024.0f) - mu * mu;
  float rs  = rsqrtf(var + 1e-5f);
  float4 gv = *(const float4*)(g + t * 4);
  float4 bv = *(const float4*)(bta + t * 4);
  float4 o;
  o.x = (v.x - mu) * rs * gv.x + bv.x;
  o.y = (v.y - mu) * rs * gv.y + bv.y;
  o.z = (v.z - mu) * rs * gv.z + bv.z;
  o.w = (v.w - mu) * rs * gv.w + bv.w;
  *(float4*)(out + (size_t)row * 1024 + t * 4) = o;
}

// ---------------------------------------------------------------------------
// Weight transpose+convert: w fp32 [1024][N] -> wT bf16 [N][1024]
// ---------------------------------------------------------------------------
__global__ __launch_bounds__(256) void wtrans_kernel(
    const float* __restrict__ wsrc, bf16_t* __restrict__ wdstT, int N) {
  __shared__ __align__(16) float tl[64][68];
  const int n0 = blockIdx.x * 64, k0 = blockIdx.y * 64;
  const int t = threadIdx.x;
  #pragma unroll
  for (int c = 0; c < 4; ++c) {
    int idx = c * 256 + t;
    int r = idx >> 4, c4 = (idx & 15) * 4;
    *(float4*)&tl[r][c4] = *(const float4*)(wsrc + (size_t)(k0 + r) * N + n0 + c4);
  }
  __syncthreads();
  #pragma unroll
  for (int c = 0; c < 2; ++c) {
    int idx = c * 256 + t;
    int nl = idx >> 3, kc = (idx & 7) * 8;
    bf16x8 o;
    #pragma unroll
    for (int ii = 0; ii < 8; ++ii) o[ii] = (bf16_t)tl[kc + ii][nl];
    *(bf16x8*)(wdstT + (size_t)(n0 + nl) * 1024 + k0 + kc) = o;
  }
}

// ---------------------------------------------------------------------------
// V transpose: v bf16 [b,h,n,64] -> vT bf16 [b,h,64,n]   (n=2048)
// ---------------------------------------------------------------------------
__global__ __launch_bounds__(256) void vtrans_kernel(
    const bf16_t* __restrict__ v, bf16_t* __restrict__ vT) {
  __shared__ __align__(16) bf16_t tl[64][72];
  const int n0 = blockIdx.x * 64;
  const size_t bh = blockIdx.y;
  const int t = threadIdx.x;
  #pragma unroll
  for (int c = 0; c < 2; ++c) {
    int idx = c * 256 + t;
    int r = idx >> 3, c8 = (idx & 7) * 8;
    *(bf16x8*)&tl[r][c8] = *(const bf16x8*)(v + (bh * 2048 + n0 + r) * 64 + c8);
  }
  __syncthreads();
  #pragma unroll
  for (int c = 0; c < 2; ++c) {
    int idx = c * 256 + t;
    int d = idx >> 3, nc = (idx & 7) * 8;
    bf16x8 o;
    #pragma unroll
    for (int ii = 0; ii < 8; ++ii) o[ii] = tl[nc + ii][d];
    *(bf16x8*)(vT + (bh * 64 + d) * 2048 + n0 + nc) = o;
  }
}

// ---------------------------------------------------------------------------
// GEMM: C[M,N] = A[M,1024] @ Bt[N,1024]^T, bf16 in, fp32 acc. (m97 structure)
// ---------------------------------------------------------------------------
template <int EPI>
__global__ __launch_bounds__(256, 2) void gemm128_kernel(
    const bf16_t* __restrict__ A, const bf16_t* __restrict__ Bt,
    void* __restrict__ C0, void* __restrict__ C1, void* __restrict__ C2) {
  __shared__ __align__(16) bf16_t As[128 * 32];
  __shared__ __align__(16) bf16_t Bs[128 * 32];
  const int t = threadIdx.x;
  const int w = t >> 6, l = t & 63, l15 = l & 15, quad = l >> 4;
  const int wy = w >> 1, wx = w & 1;
  const int m0 = blockIdx.y * 128, n0 = blockIdx.x * 128;

  int arow[2], acol[2];
  #pragma unroll
  for (int c = 0; c < 2; ++c) {
    int e = (w * 2 + c) * 512 + l * 8;
    arow[c] = e >> 5;
    acol[c] = e & 31;
  }

  f32x4 acc[4][4];
  #pragma unroll
  for (int i = 0; i < 4; ++i)
    #pragma unroll
    for (int j = 0; j < 4; ++j) acc[i][j] = (f32x4)0.0f;

  for (int kt = 0; kt < 32; ++kt) {
    __syncthreads();
    #pragma unroll
    for (int c = 0; c < 2; ++c) {
      async_copy16(&As[(w * 2 + c) * 512],
                   A + (size_t)(m0 + arow[c]) * 1024 + kt * 32 + acol[c]);
      async_copy16(&Bs[(w * 2 + c) * 512],
                   Bt + (size_t)(n0 + arow[c]) * 1024 + kt * 32 + acol[c]);
    }
    __syncthreads();
    bf16x8 af[4], bfr[4];
    #pragma unroll
    for (int i = 0; i < 4; ++i)
      af[i] = *(const bf16x8*)&As[(wy * 64 + i * 16 + l15) * 32 + quad * 8];
    #pragma unroll
    for (int j = 0; j < 4; ++j)
      bfr[j] = *(const bf16x8*)&Bs[(wx * 64 + j * 16 + l15) * 32 + quad * 8];
    #pragma unroll
    for (int i = 0; i < 4; ++i)
      #pragma unroll
      for (int j = 0; j < 4; ++j)
        acc[i][j] = __builtin_amdgcn_mfma_f32_16x16x32_bf16(af[i], bfr[j], acc[i][j], 0, 0, 0);
  }

  if (EPI == 0) {
    float* C = (float*)C0;
    #pragma unroll
    for (int i = 0; i < 4; ++i)
      #pragma unroll
      for (int j = 0; j < 4; ++j)
        #pragma unroll
        for (int r = 0; r < 4; ++r) {
          int m = m0 + wy * 64 + i * 16 + quad * 4 + r;
          int n = n0 + wx * 64 + j * 16 + l15;
          C[(size_t)m * 1024 + n] = acc[i][j][r];
        }
  } else {
    int nb = n0 + wx * 64;
    int which = nb >> 10;
    int head = (nb & 1023) >> 6;
    bf16_t* dst = which == 0 ? (bf16_t*)C0 : which == 1 ? (bf16_t*)C1 : (bf16_t*)C2;
    float sc = which == 0 ? 0.125f : 1.0f;
    #pragma unroll
    for (int i = 0; i < 4; ++i)
      #pragma unroll
      for (int j = 0; j < 4; ++j)
        #pragma unroll
        for (int r = 0; r < 4; ++r) {
          int m = m0 + wy * 64 + i * 16 + quad * 4 + r;
          int bq = m >> 11, pos = m & 2047;
          int d = j * 16 + l15;
          dst[(((size_t)(bq * 16 + head)) * 2048 + pos) * 64 + d] =
              (bf16_t)(acc[i][j][r] * sc);
        }
  }
}

// ---------------------------------------------------------------------------
// Causal ReLU attention, R3.
// Block = (pair p, h, b): sub-tiles tA=p, tB=31-p (uniform 33 key-units).
// Wave w owns rows [w*16,w*16+16) of each sub-tile. K/V staged to LDS via
// global_load_lds (zero VGPRs, shared by 4 waves & both sub-tiles), double
// buffered, ONE barrier per key-tile. LDS layout XOR-swizzled
// (unit ^= row&7) applied on the GLOBAL source address so b128 fragment
// reads are 2-way (free). Ss C->A round-trip wave-private (no barrier).
// q,k: [b,h,2048,64] bf16 (q pre-scaled). vT: [b,h,64,2048]. out: [b,2048,1024].
// ---------------------------------------------------------------------------
__global__ __launch_bounds__(256, 2) void attn_kernel(
    const bf16_t* __restrict__ q, const bf16_t* __restrict__ k,
    const bf16_t* __restrict__ vT, bf16_t* __restrict__ out) {
  __shared__ __align__(16) bf16_t Ks[2][64 * 64];   // 2 x 8 KB
  __shared__ __align__(16) bf16_t Vts[2][64 * 64];  // 2 x 8 KB  ([d][j] swizzled)
  __shared__ __align__(16) bf16_t Ss[64 * 72];      // 9 KB, wave-private rows

  const int p = blockIdx.x, h = blockIdx.y, b = blockIdx.z;
  const int t = threadIdx.x;
  const int w = t >> 6, l = t & 63, l15 = l & 15, quad = l >> 4;
  const size_t bh = (size_t)(b * 16 + h);
  const int tidx[2] = {p, 31 - p};
  const int nkt = tidx[1] + 1;

  // staging geometry (per wave: chunks idx=w*2+c for K and for V)
  const int r_l = l >> 3;                 // row within 8-row chunk
  const int u_g = (l & 7) ^ r_l;          // swizzled source 8-elem unit
  const int rswz = l15 & 7;               // read-side swizzle key

  // Q A-fragments in registers (plain global loads, once)
  bf16x8 qa[2][2];
  #pragma unroll
  for (int tt = 0; tt < 2; ++tt) {
    int r0 = tidx[tt] * 64 + w * 16;
    #pragma unroll
    for (int kk = 0; kk < 2; ++kk)
      qa[tt][kk] = *(const bf16x8*)(q + (bh * 2048 + r0 + l15) * 64 + kk * 32 + quad * 8);
  }

  f32x4 acc[2][4];
  #pragma unroll
  for (int tt = 0; tt < 2; ++tt)
    #pragma unroll
    for (int tj = 0; tj < 4; ++tj) acc[tt][tj] = (f32x4)0.0f;

  // prefetch tile 0 into buffer 0
  #pragma unroll
  for (int c = 0; c < 2; ++c) {
    int idx = w * 2 + c;
    int row = idx * 8 + r_l;
    async_copy16(&Ks[0][idx * 512],  k  + (bh * 2048 + row) * 64 + u_g * 8);
    async_copy16(&Vts[0][idx * 512], vT + (bh * 64 + row) * 2048 + u_g * 8);
  }

  for (int kt = 0; kt < nkt; ++kt) {
    __syncthreads();  // drains own async loads (vmcnt) + fences buffer reuse
    if (kt + 1 < nkt) {
      int nb = (kt + 1) & 1;
      #pragma unroll
      for (int c = 0; c < 2; ++c) {
        int idx = w * 2 + c;
        int row = idx * 8 + r_l;
        async_copy16(&Ks[nb][idx * 512],
                     k + (bh * 2048 + (kt + 1) * 64 + row) * 64 + u_g * 8);
        async_copy16(&Vts[nb][idx * 512],
                     vT + (bh * 64 + row) * 2048 + (kt + 1) * 64 + u_g * 8);
      }
    }
    const bf16_t* Kb = Ks[kt & 1];
    const bf16_t* Vb = Vts[kt & 1];

    // fragments read once, shared by both sub-tiles (swizzled units)
    bf16x8 bk[2][4], bv[2][4];
    #pragma unroll
    for (int kk = 0; kk < 2; ++kk)
      #pragma unroll
      for (int tj = 0; tj < 4; ++tj) {
        int u = ((kk * 4 + quad) ^ rswz) * 8;
        bk[kk][tj] = *(const bf16x8*)&Kb[(tj * 16 + l15) * 64 + u];
        bv[kk][tj] = *(const bf16x8*)&Vb[(tj * 16 + l15) * 64 + u];
      }

    #pragma unroll
    for (int tt = 0; tt < 2; ++tt) {
      if (kt <= tidx[tt]) {  // block-uniform; tt compile-time
        f32x4 sacc[4];
        #pragma unroll
        for (int tj = 0; tj < 4; ++tj) sacc[tj] = (f32x4)0.0f;
        #pragma unroll
        for (int kk = 0; kk < 2; ++kk)
          #pragma unroll
          for (int tj = 0; tj < 4; ++tj)
            sacc[tj] = __builtin_amdgcn_mfma_f32_16x16x32_bf16(qa[tt][kk], bk[kk][tj], sacc[tj], 0, 0, 0);

        const bool dg = (kt == tidx[tt]);
        #pragma unroll
        for (int tj = 0; tj < 4; ++tj)
          #pragma unroll
          for (int r = 0; r < 4; ++r) {
            float v = fmaxf(sacc[tj][r], 0.0f);
            if (dg && (tj * 16 + l15 > w * 16 + quad * 4 + r)) v = 0.0f;
            Ss[(w * 16 + quad * 4 + r) * 72 + tj * 16 + l15] = (bf16_t)v;
          }
        #pragma unroll
        for (int kk = 0; kk < 2; ++kk) {
          bf16x8 as_ = *(const bf16x8*)&Ss[(w * 16 + l15) * 72 + kk * 32 + quad * 8];
          #pragma unroll
          for (int tj = 0; tj < 4; ++tj)
            acc[tt][tj] = __builtin_amdgcn_mfma_f32_16x16x32_bf16(as_, bv[kk][tj], acc[tt][tj], 0, 0, 0);
        }
      }
    }
  }

  // epilogue: out[b][pos][h*64+d]
  #pragma unroll
  for (int tt = 0; tt < 2; ++tt)
    #pragma unroll
    for (int tj = 0; tj < 4; ++tj)
      #pragma unroll
      for (int r = 0; r < 4; ++r) {
        int pos = tidx[tt] * 64 + w * 16 + quad * 4 + r;
        int col = h * 64 + tj * 16 + l15;
        out[((size_t)b * 2048 + pos) * 1024 + col] = (bf16_t)acc[tt][tj][r];
      }
}

// ---------------------------------------------------------------------------
// launch
// ---------------------------------------------------------------------------
extern "C" void kernel_launch(void* const* d_in, const int* in_sizes, int n_in,
                              void* d_out, int out_size, void* d_ws, size_t ws_size,
                              hipStream_t stream) {
  (void)in_sizes; (void)n_in; (void)out_size; (void)ws_size;
  const float* x     = (const float*)d_in[0];
  const float* ln1_g = (const float*)d_in[1];
  const float* ln1_b = (const float*)d_in[2];
  const float* w_qkv = (const float*)d_in[3];
  const float* w_out = (const float*)d_in[4];
  const float* ln2_g = (const float*)d_in[5];
  const float* ln2_b = (const float*)d_in[6];
  float* out = (float*)d_out;

  char* ws = (char*)d_ws;
  bf16_t* xn     = (bf16_t*)(ws + 0);          //  8,388,608  [4096,1024]
  bf16_t* wqkvT  = (bf16_t*)(ws + 8388608);    //  6,291,456  [3072,1024]
  bf16_t* woutT  = (bf16_t*)(ws + 14680064);   //  2,097,152  [1024,1024]
  bf16_t* qb     = (bf16_t*)(ws + 16777216);   //  8,388,608  [2,16,2048,64]
  bf16_t* kb     = (bf16_t*)(ws + 25165824);   //  8,388,608
  bf16_t* vb     = (bf16_t*)(ws + 33554432);   //  8,388,608
  bf16_t* vTb    = (bf16_t*)(ws + 41943040);   //  8,388,608  [2,16,64,2048]
  bf16_t* ao     = (bf16_t*)(ws + 50331648);   //  8,388,608  [4096,1024]
  float*  z      = (float*)(ws + 58720256);    // 16,777,216  [4096,1024]

  ln1_kernel<<<4096, 256, 0, stream>>>(x, ln1_g, ln1_b, xn);
  wtrans_kernel<<<dim3(48, 16), 256, 0, stream>>>(w_qkv, wqkvT, 3072);
  wtrans_kernel<<<dim3(16, 16), 256, 0, stream>>>(w_out, woutT, 1024);
  gemm128_kernel<1><<<dim3(24, 32), 256, 0, stream>>>(xn, wqkvT, qb, kb, vb);
  vtrans_kernel<<<dim3(32, 32), 256, 0, stream>>>(vb, vTb);
  attn_kernel<<<dim3(16, 16, 2), 256, 0, stream>>>(qb, kb, vTb, ao);
  gemm128_kernel<0><<<dim3(8, 32), 256, 0, stream>>>(ao, woutT, z, nullptr, nullptr);
  ln2_kernel<<<4096, 256, 0, stream>>>(z, ln2_g, ln2_b, out);
}

// Round 6
// 194.117 us; speedup vs baseline: 1.6376x; 1.0229x over previous
//
#include <hip/hip_runtime.h>
#include <cstdint>
#include <cstddef>

// ---------------------------------------------------------------------------
// ReLA block: y = LN2( (causal_relu( (LN1(x)Wq*s) (LN1(x)Wk)^T ) (LN1(x)Wv)) Wout )
// x: [2,2048,1024] fp32. HEADS=16, DIM_HEAD=64, DIM=1024. Output fp32.
// bf16 MFMA (16x16x32) everywhere, fp32 accumulate.
// R5 = R4 with the split-K plumbing bug fixed: partial kz=1 now goes to an
//     explicitly-passed z1 pointer (R4 wrote it 16MB past z0 while LN2 read
//     the dead qb region -> absmax 4.6).
// ---------------------------------------------------------------------------

typedef __bf16 bf16_t;
typedef __bf16 bf16x8 __attribute__((ext_vector_type(8)));
typedef __bf16 bf16x4 __attribute__((ext_vector_type(4)));
typedef float  f32x4  __attribute__((ext_vector_type(4)));

#define DEV_INLINE __device__ __forceinline__

// async global->LDS, 16B per lane. LDS dest is wave-uniform base + lane*16.
DEV_INLINE void async_copy16(void* lds, const void* g) {
  __builtin_amdgcn_global_load_lds(
      (__attribute__((address_space(1))) void*)(g),
      (__attribute__((address_space(3))) void*)(lds), 16, 0, 0);
}

// ---------------------------------------------------------------------------
// LN1: x fp32 [4096,1024] -> xn bf16 [4096,1024]
// ---------------------------------------------------------------------------
__global__ __launch_bounds__(256) void ln1_kernel(
    const float* __restrict__ x, const float* __restrict__ g,
    const float* __restrict__ bta, bf16_t* __restrict__ xn) {
  const int row = blockIdx.x;
  const int t = threadIdx.x, w = t >> 6, l = t & 63;
  const float* xr = x + (size_t)row * 1024;
  float4 v = *(const float4*)(xr + t * 4);
  float s  = v.x + v.y + v.z + v.w;
  float s2 = v.x * v.x + v.y * v.y + v.z * v.z + v.w * v.w;
  #pragma unroll
  for (int off = 32; off >= 1; off >>= 1) {
    s  += __shfl_down(s, off);
    s2 += __shfl_down(s2, off);
  }
  __shared__ float red[8];
  if (l == 0) { red[w] = s; red[4 + w] = s2; }
  __syncthreads();
  s  = red[0] + red[1] + red[2] + red[3];
  s2 = red[4] + red[5] + red[6] + red[7];
  float mu  = s * (1.0f / 1024.0f);
  float var = s2 * (1.0f / 1024.0f) - mu * mu;
  float rs  = rsqrtf(var + 1e-5f);
  float4 gv = *(const float4*)(g + t * 4);
  float4 bv = *(const float4*)(bta + t * 4);
  bf16x4 o;
  o[0] = (bf16_t)((v.x - mu) * rs * gv.x + bv.x);
  o[1] = (bf16_t)((v.y - mu) * rs * gv.y + bv.y);
  o[2] = (bf16_t)((v.z - mu) * rs * gv.z + bv.z);
  o[3] = (bf16_t)((v.w - mu) * rs * gv.w + bv.w);
  *(bf16x4*)(xn + (size_t)row * 1024 + t * 4) = o;
}

// ---------------------------------------------------------------------------
// LN2 (fused split-K add): z = z0 + z1, then layernorm -> out fp32
// ---------------------------------------------------------------------------
__global__ __launch_bounds__(256) void ln2_kernel(
    const float* __restrict__ z0, const float* __restrict__ z1,
    const float* __restrict__ g, const float* __restrict__ bta,
    float* __restrict__ out) {
  const int row = blockIdx.x;
  const int t = threadIdx.x, w = t >> 6, l = t & 63;
  float4 v  = *(const float4*)(z0 + (size_t)row * 1024 + t * 4);
  float4 v1 = *(const float4*)(z1 + (size_t)row * 1024 + t * 4);
  v.x += v1.x; v.y += v1.y; v.z += v1.z; v.w += v1.w;
  float s  = v.x + v.y + v.z + v.w;
  float s2 = v.x * v.x + v.y * v.y + v.z * v.z + v.w * v.w;
  #pragma unroll
  for (int off = 32; off >= 1; off >>= 1) {
    s  += __shfl_down(s, off);
    s2 += __shfl_down(s2, off);
  }
  __shared__ float red[8];
  if (l == 0) { red[w] = s; red[4 + w] = s2; }
  __syncthreads();
  s  = red[0] + red[1] + red[2] + red[3];
  s2 = red[4] + red[5] + red[6] + red[7];
  float mu  = s * (1.0f / 1024.0f);
  float var = s2 * (1.0f / 1024.0f) - mu * mu;
  float rs  = rsqrtf(var + 1e-5f);
  float4 gv = *(const float4*)(g + t * 4);
  float4 bv = *(const float4*)(bta + t * 4);
  float4 o;
  o.x = (v.x - mu) * rs * gv.x + bv.x;
  o.y = (v.y - mu) * rs * gv.y + bv.y;
  o.z = (v.z - mu) * rs * gv.z + bv.z;
  o.w = (v.w - mu) * rs * gv.w + bv.w;
  *(float4*)(out + (size_t)row * 1024 + t * 4) = o;
}

// ---------------------------------------------------------------------------
// Weight transpose+convert: w fp32 [1024][N] -> wT bf16 [N][1024]
// ---------------------------------------------------------------------------
__global__ __launch_bounds__(256) void wtrans_kernel(
    const float* __restrict__ wsrc, bf16_t* __restrict__ wdstT, int N) {
  __shared__ __align__(16) float tl[64][68];
  const int n0 = blockIdx.x * 64, k0 = blockIdx.y * 64;
  const int t = threadIdx.x;
  #pragma unroll
  for (int c = 0; c < 4; ++c) {
    int idx = c * 256 + t;
    int r = idx >> 4, c4 = (idx & 15) * 4;
    *(float4*)&tl[r][c4] = *(const float4*)(wsrc + (size_t)(k0 + r) * N + n0 + c4);
  }
  __syncthreads();
  #pragma unroll
  for (int c = 0; c < 2; ++c) {
    int idx = c * 256 + t;
    int nl = idx >> 3, kc = (idx & 7) * 8;
    bf16x8 o;
    #pragma unroll
    for (int ii = 0; ii < 8; ++ii) o[ii] = (bf16_t)tl[kc + ii][nl];
    *(bf16x8*)(wdstT + (size_t)(n0 + nl) * 1024 + k0 + kc) = o;
  }
}

// ---------------------------------------------------------------------------
// V transpose: v bf16 [b,h,n,64] -> vT bf16 [b,h,64,n]   (n=2048)
// ---------------------------------------------------------------------------
__global__ __launch_bounds__(256) void vtrans_kernel(
    const bf16_t* __restrict__ v, bf16_t* __restrict__ vT) {
  __shared__ __align__(16) bf16_t tl[64][72];
  const int n0 = blockIdx.x * 64;
  const size_t bh = blockIdx.y;
  const int t = threadIdx.x;
  #pragma unroll
  for (int c = 0; c < 2; ++c) {
    int idx = c * 256 + t;
    int r = idx >> 3, c8 = (idx & 7) * 8;
    *(bf16x8*)&tl[r][c8] = *(const bf16x8*)(v + (bh * 2048 + n0 + r) * 64 + c8);
  }
  __syncthreads();
  #pragma unroll
  for (int c = 0; c < 2; ++c) {
    int idx = c * 256 + t;
    int d = idx >> 3, nc = (idx & 7) * 8;
    bf16x8 o;
    #pragma unroll
    for (int ii = 0; ii < 8; ++ii) o[ii] = tl[nc + ii][d];
    *(bf16x8*)(vT + (bh * 64 + d) * 2048 + n0 + nc) = o;
  }
}

// ---------------------------------------------------------------------------
// GEMM: C[M,N] = A[M,1024] @ Bt[N,1024]^T, bf16 in, fp32 acc.
// KSPLIT=2: blockIdx.z picks K-half; kz=0 -> C0, kz=1 -> C1 (fp32 partials).
// EPI=1: qkv split epilogue -> q(*0.125)/k/v bf16 [b,h,2048,64].
// ---------------------------------------------------------------------------
template <int EPI, int KSPLIT>
__global__ __launch_bounds__(256, 3) void gemm128_kernel(
    const bf16_t* __restrict__ A, const bf16_t* __restrict__ Bt,
    void* __restrict__ C0, void* __restrict__ C1, void* __restrict__ C2) {
  __shared__ __align__(16) bf16_t As[128 * 32];
  __shared__ __align__(16) bf16_t Bs[128 * 32];
  const int t = threadIdx.x;
  const int w = t >> 6, l = t & 63, l15 = l & 15, quad = l >> 4;
  const int wy = w >> 1, wx = w & 1;
  const int m0 = blockIdx.y * 128, n0 = blockIdx.x * 128;
  const int kz = (KSPLIT > 1) ? blockIdx.z : 0;
  const int kt0 = kz * (32 / KSPLIT), kt1 = kt0 + (32 / KSPLIT);

  int arow[2], acol[2];
  #pragma unroll
  for (int c = 0; c < 2; ++c) {
    int e = (w * 2 + c) * 512 + l * 8;
    arow[c] = e >> 5;
    acol[c] = e & 31;
  }

  f32x4 acc[4][4];
  #pragma unroll
  for (int i = 0; i < 4; ++i)
    #pragma unroll
    for (int j = 0; j < 4; ++j) acc[i][j] = (f32x4)0.0f;

  for (int kt = kt0; kt < kt1; ++kt) {
    __syncthreads();
    #pragma unroll
    for (int c = 0; c < 2; ++c) {
      async_copy16(&As[(w * 2 + c) * 512],
                   A + (size_t)(m0 + arow[c]) * 1024 + kt * 32 + acol[c]);
      async_copy16(&Bs[(w * 2 + c) * 512],
                   Bt + (size_t)(n0 + arow[c]) * 1024 + kt * 32 + acol[c]);
    }
    __syncthreads();
    bf16x8 af[4], bfr[4];
    #pragma unroll
    for (int i = 0; i < 4; ++i)
      af[i] = *(const bf16x8*)&As[(wy * 64 + i * 16 + l15) * 32 + quad * 8];
    #pragma unroll
    for (int j = 0; j < 4; ++j)
      bfr[j] = *(const bf16x8*)&Bs[(wx * 64 + j * 16 + l15) * 32 + quad * 8];
    #pragma unroll
    for (int i = 0; i < 4; ++i)
      #pragma unroll
      for (int j = 0; j < 4; ++j)
        acc[i][j] = __builtin_amdgcn_mfma_f32_16x16x32_bf16(af[i], bfr[j], acc[i][j], 0, 0, 0);
  }

  if (EPI == 0) {
    float* C = (float*)(kz == 0 ? C0 : C1);   // explicit partial destinations
    #pragma unroll
    for (int i = 0; i < 4; ++i)
      #pragma unroll
      for (int j = 0; j < 4; ++j)
        #pragma unroll
        for (int r = 0; r < 4; ++r) {
          int m = m0 + wy * 64 + i * 16 + quad * 4 + r;
          int n = n0 + wx * 64 + j * 16 + l15;
          C[(size_t)m * 1024 + n] = acc[i][j][r];
        }
  } else {
    int nb = n0 + wx * 64;
    int which = nb >> 10;
    int head = (nb & 1023) >> 6;
    bf16_t* dst = which == 0 ? (bf16_t*)C0 : which == 1 ? (bf16_t*)C1 : (bf16_t*)C2;
    float sc = which == 0 ? 0.125f : 1.0f;
    #pragma unroll
    for (int i = 0; i < 4; ++i)
      #pragma unroll
      for (int j = 0; j < 4; ++j)
        #pragma unroll
        for (int r = 0; r < 4; ++r) {
          int m = m0 + wy * 64 + i * 16 + quad * 4 + r;
          int bq = m >> 11, pos = m & 2047;
          int d = j * 16 + l15;
          dst[(((size_t)(bq * 16 + head)) * 2048 + pos) * 64 + d] =
              (bf16_t)(acc[i][j][r] * sc);
        }
  }
}

// ---------------------------------------------------------------------------
// Causal ReLU attention, R4 schedule: uniform 17 iterations, XCD-local grid.
// Block (h=bx, p=by, b=bz): sub-tiles tA=p, tB=31-p (33 key-units).
// Phase 1 (it<=p): stage 64 keys, compute both sub-tiles.
// Phase 2 (it>p):  stage 128 keys (2 tiles), compute tile B twice
//                  (2nd skipped beyond diagonal) -> exactly 17 iterations.
// K/V double-buffered via global_load_lds (swizzled), Ss wave-private.
// ---------------------------------------------------------------------------
__global__ __launch_bounds__(256, 2) void attn_kernel(
    const bf16_t* __restrict__ q, const bf16_t* __restrict__ k,
    const bf16_t* __restrict__ vT, bf16_t* __restrict__ out) {
  __shared__ __align__(16) bf16_t Ks[2][128 * 64];   // 2 x 16 KB (two 64-key halves)
  __shared__ __align__(16) bf16_t Vts[2][128 * 64];  // 2 x 16 KB
  __shared__ __align__(16) bf16_t Ss[64 * 72];       // 9 KB, wave-private rows

  const int h = blockIdx.x, p = blockIdx.y, b = blockIdx.z;
  const int t = threadIdx.x;
  const int w = t >> 6, l = t & 63, l15 = l & 15, quad = l >> 4;
  const size_t bh = (size_t)(b * 16 + h);
  const int tB = 31 - p;

  const int r_l = l >> 3;            // row within 8-row chunk
  const int u_g = (l & 7) ^ r_l;     // swizzled source 8-elem unit
  const int rswz = l15 & 7;          // read-side swizzle key

  auto stage_tile = [&](int buf, int half, int kt2) {
    #pragma unroll
    for (int c = 0; c < 2; ++c) {
      int idx = w * 2 + c;                    // 0..7
      int row = idx * 8 + r_l;                // 0..63
      async_copy16(&Ks[buf][half * 4096 + idx * 512],
                   k + (bh * 2048 + kt2 * 64 + row) * 64 + u_g * 8);
      async_copy16(&Vts[buf][half * 4096 + idx * 512],
                   vT + (bh * 64 + row) * 2048 + kt2 * 64 + u_g * 8);
    }
  };
  auto stage_it = [&](int it, int buf) {
    if (it <= p) {
      stage_tile(buf, 0, it);
    } else {
      int base = p + 1 + 2 * (it - p - 1);
      stage_tile(buf, 0, base);
      int k2 = base + 1; if (k2 > 31) k2 = 31;  // clamp (compute skips > tB)
      stage_tile(buf, 1, k2);
    }
  };

  bf16x8 qa[2][2];
  {
    int rA = p * 64 + w * 16, rB = tB * 64 + w * 16;
    #pragma unroll
    for (int kk = 0; kk < 2; ++kk) {
      qa[0][kk] = *(const bf16x8*)(q + (bh * 2048 + rA + l15) * 64 + kk * 32 + quad * 8);
      qa[1][kk] = *(const bf16x8*)(q + (bh * 2048 + rB + l15) * 64 + kk * 32 + quad * 8);
    }
  }

  f32x4 acc0[4], acc1[4];
  #pragma unroll
  for (int tj = 0; tj < 4; ++tj) { acc0[tj] = (f32x4)0.0f; acc1[tj] = (f32x4)0.0f; }

  auto unit = [&](f32x4 (&accr)[4], bf16x8 (&qf)[2],
                  const bf16_t* Kb, const bf16_t* Vb, bool dg) {
    f32x4 sacc[4];
    #pragma unroll
    for (int tj = 0; tj < 4; ++tj) sacc[tj] = (f32x4)0.0f;
    #pragma unroll
    for (int kk = 0; kk < 2; ++kk)
      #pragma unroll
      for (int tj = 0; tj < 4; ++tj) {
        bf16x8 bk = *(const bf16x8*)&Kb[(tj * 16 + l15) * 64 + (((kk * 4 + quad) ^ rswz) * 8)];
        sacc[tj] = __builtin_amdgcn_mfma_f32_16x16x32_bf16(qf[kk], bk, sacc[tj], 0, 0, 0);
      }
    #pragma unroll
    for (int tj = 0; tj < 4; ++tj)
      #pragma unroll
      for (int r = 0; r < 4; ++r) {
        float v = fmaxf(sacc[tj][r], 0.0f);
        if (dg && (tj * 16 + l15 > w * 16 + quad * 4 + r)) v = 0.0f;
        Ss[(w * 16 + quad * 4 + r) * 72 + tj * 16 + l15] = (bf16_t)v;
      }
    #pragma unroll
    for (int kk = 0; kk < 2; ++kk) {
      bf16x8 as_ = *(const bf16x8*)&Ss[(w * 16 + l15) * 72 + kk * 32 + quad * 8];
      #pragma unroll
      for (int tj = 0; tj < 4; ++tj) {
        bf16x8 bv = *(const bf16x8*)&Vb[(tj * 16 + l15) * 64 + (((kk * 4 + quad) ^ rswz) * 8)];
        accr[tj] = __builtin_amdgcn_mfma_f32_16x16x32_bf16(as_, bv, accr[tj], 0, 0, 0);
      }
    }
  };

  stage_it(0, 0);
  for (int it = 0; it < 17; ++it) {
    __syncthreads();  // drains this buffer's async loads; fences reuse
    if (it + 1 < 17) stage_it(it + 1, (it + 1) & 1);
    const int buf = it & 1;
    if (it <= p) {
      unit(acc0, qa[0], &Ks[buf][0], &Vts[buf][0], it == p);
      unit(acc1, qa[1], &Ks[buf][0], &Vts[buf][0], false);
    } else {
      int base = p + 1 + 2 * (it - p - 1);
      unit(acc1, qa[1], &Ks[buf][0], &Vts[buf][0], base == tB);
      if (base + 1 <= tB)
        unit(acc1, qa[1], &Ks[buf][4096], &Vts[buf][4096], base + 1 == tB);
    }
  }

  // epilogue: out[b][pos][h*64+d]
  #pragma unroll
  for (int tj = 0; tj < 4; ++tj)
    #pragma unroll
    for (int r = 0; r < 4; ++r) {
      int col = h * 64 + tj * 16 + l15;
      int posA = p * 64 + w * 16 + quad * 4 + r;
      int posB = tB * 64 + w * 16 + quad * 4 + r;
      out[((size_t)b * 2048 + posA) * 1024 + col] = (bf16_t)acc0[tj][r];
      out[((size_t)b * 2048 + posB) * 1024 + col] = (bf16_t)acc1[tj][r];
    }
}

// ---------------------------------------------------------------------------
// launch
// ---------------------------------------------------------------------------
extern "C" void kernel_launch(void* const* d_in, const int* in_sizes, int n_in,
                              void* d_out, int out_size, void* d_ws, size_t ws_size,
                              hipStream_t stream) {
  (void)in_sizes; (void)n_in; (void)out_size; (void)ws_size;
  const float* x     = (const float*)d_in[0];
  const float* ln1_g = (const float*)d_in[1];
  const float* ln1_b = (const float*)d_in[2];
  const float* w_qkv = (const float*)d_in[3];
  const float* w_out = (const float*)d_in[4];
  const float* ln2_g = (const float*)d_in[5];
  const float* ln2_b = (const float*)d_in[6];
  float* out = (float*)d_out;

  char* ws = (char*)d_ws;
  bf16_t* xn     = (bf16_t*)(ws + 0);          //  8,388,608  [4096,1024]
  bf16_t* wqkvT  = (bf16_t*)(ws + 8388608);    //  6,291,456  [3072,1024]
  bf16_t* woutT  = (bf16_t*)(ws + 14680064);   //  2,097,152  [1024,1024]
  bf16_t* qb     = (bf16_t*)(ws + 16777216);   //  8,388,608  [2,16,2048,64]
  bf16_t* kb     = (bf16_t*)(ws + 25165824);   //  8,388,608
  bf16_t* vb     = (bf16_t*)(ws + 33554432);   //  8,388,608
  bf16_t* vTb    = (bf16_t*)(ws + 41943040);   //  8,388,608  [2,16,64,2048]
  bf16_t* ao     = (bf16_t*)(ws + 50331648);   //  8,388,608  [4096,1024]
  float*  z0     = (float*)(ws + 58720256);    // 16,777,216  [4096,1024]
  float*  z1     = (float*)(ws + 16777216);    // 16 MB, reuses qb+kb (dead after attn)

  ln1_kernel<<<4096, 256, 0, stream>>>(x, ln1_g, ln1_b, xn);
  wtrans_kernel<<<dim3(48, 16), 256, 0, stream>>>(w_qkv, wqkvT, 3072);
  wtrans_kernel<<<dim3(16, 16), 256, 0, stream>>>(w_out, woutT, 1024);
  gemm128_kernel<1, 1><<<dim3(24, 32), 256, 0, stream>>>(xn, wqkvT, qb, kb, vb);
  vtrans_kernel<<<dim3(32, 32), 256, 0, stream>>>(vb, vTb);
  attn_kernel<<<dim3(16, 16, 2), 256, 0, stream>>>(qb, kb, vTb, ao);
  gemm128_kernel<0, 2><<<dim3(8, 32, 2), 256, 0, stream>>>(ao, woutT, z0, z1, nullptr);
  ln2_kernel<<<4096, 256, 0, stream>>>(z0, z1, ln2_g, ln2_b, out);
}